// Round 7
// baseline (262.645 us; speedup 1.0000x reference)
//
#include <hip/hip_runtime.h>
#include <hip/hip_bf16.h>

// ContrastiveLoss: B=4096 rows, D=128 feature dim, C=100 classes.
// loss = -(1/B^2) * sum_c count_c * G_c / (count_c + 1e-12)
//   G_c  = sum_{k: label_k=c} S_k
//   S_k  = sum_j logits[k,j] - B*m_k - B*log(Z_k + 1e-12)
//   logits[k,j] = w_k . a_j,  w_k = (a_k + (a_k @ Cov[l_k]) / (2 T^2)) / T
// 4 dispatches: sort (histogram + parallel scan + counting sort + zero ctl),
// wbuild (one block per class-tile: 400-way parallel Cov stream), main (MFMA
// flash logits; 3 blocks/CU, PITCH 132), combine (merge + ticketed final).
// NOTE: heavy epilogue code must stay OUT of main_kernel — R4 showed fusing
// the double-precision tail in wrecks regalloc (VGPR 68, spills, 115us).

#define DIM 128
#define TEMP 0.07f
#define PITCH 132  // LDS row pitch in bf16 (128+4): stride 66 words -> bank 2r%32
#define RT 32      // rows per class tile in wbuild
#define TILES 4    // max tiles per class (128 rows; multinomial max ~60)

typedef __attribute__((ext_vector_type(8))) short short8;
typedef __attribute__((ext_vector_type(4))) float floatx4;

static __device__ __forceinline__ unsigned short f2bf(float f) {
    __hip_bfloat16 h = __float2bfloat16(f);
    union { __hip_bfloat16 h; unsigned short u; } c;
    c.h = h;
    return c.u;
}

// Single block: histogram labels, shfl parallel scan, counting-sort row
// indices into order[], emit counts/classStart, zero G + ticket.
__global__ __launch_bounds__(1024) void sort_kernel(
    const int* __restrict__ labels, int* __restrict__ order,
    int* __restrict__ classStart, int* __restrict__ counts,
    double* __restrict__ G, int* __restrict__ ticket, int B, int C) {
    __shared__ int hist[128];
    __shared__ int offs[128];
    __shared__ int w0tot;
    int t = threadIdx.x;
    if (t < 128) hist[t] = 0;
    __syncthreads();
    for (int i = t; i < B; i += 1024) atomicAdd(&hist[labels[i]], 1);
    __syncthreads();
    if (t < 128) {
        int h = hist[t];
        int v = h;
        int lane = t & 63;
#pragma unroll
        for (int o = 1; o < 64; o <<= 1) {
            int u = __shfl_up(v, o);
            if (lane >= o) v += u;
        }
        if (t == 63) w0tot = v;
        __syncthreads();
        if (t >= 64) v += w0tot;
        offs[t] = v - h;  // exclusive prefix
    } else {
        __syncthreads();
    }
    __syncthreads();
    if (t < 128) {
        if (t <= C) classStart[t] = (t < 128) ? offs[t] : 0;
        if (t < C) { counts[t] = hist[t]; G[t] = 0.0; }
        if (t == 127) *ticket = 0;
        hist[t] = offs[t];  // reuse as running offsets
    }
    __syncthreads();
    for (int i = t; i < B; i += 1024) {
        int pos = atomicAdd(&hist[labels[i]], 1);
        order[pos] = i;
    }
}

// One block per (class, tile): transpose up to RT=32 a-rows into LDS
// (aT[d][r], bank = r -> conflict-free), then each thread accumulates
// acc[4 rows][4 cols] streaming Cov[c] rows from global. Writes Abf rows too.
__global__ __launch_bounds__(256) void wbuild_kernel(
    const float* __restrict__ A, const float* __restrict__ Cov,
    const int* __restrict__ order, const int* __restrict__ classStart,
    unsigned short* __restrict__ Wbf, unsigned short* __restrict__ Abf) {
    const float inv2t2 = 1.0f / (2.0f * TEMP * TEMP);
    const float invt = 1.0f / TEMP;
    const int c = blockIdx.x / TILES;
    const int tile = blockIdx.x % TILES;
    const int r0 = classStart[c] + tile * RT;
    const int end = classStart[c + 1];
    if (r0 >= end) return;
    int nr = end - r0;
    if (nr > RT) nr = RT;
    const int t = threadIdx.x;
    __shared__ float aT[DIM][RT];  // [d][row] 16 KB
    const float* CovC = Cov + (size_t)c * DIM * DIM;

    {   // load rows (lane owns row -> conflict-free transpose), cast Abf
        int rl = t & 31, dseg = (t >> 5) * 16;
        if (rl < nr) {
            int row = order[r0 + rl];
            const float4* src = (const float4*)(A + (size_t)row * DIM + dseg);
            float4 v[4];
#pragma unroll
            for (int i = 0; i < 4; ++i) v[i] = src[i];
            ushort4* ad = (ushort4*)(Abf + (size_t)row * DIM + dseg);
#pragma unroll
            for (int i = 0; i < 4; ++i) {
                ushort4 o;
                o.x = f2bf(v[i].x); o.y = f2bf(v[i].y);
                o.z = f2bf(v[i].z); o.w = f2bf(v[i].w);
                ad[i] = o;
            }
#pragma unroll
            for (int i = 0; i < 4; ++i) {
                aT[dseg + i * 4 + 0][rl] = v[i].x;
                aT[dseg + i * 4 + 1][rl] = v[i].y;
                aT[dseg + i * 4 + 2][rl] = v[i].z;
                aT[dseg + i * 4 + 3][rl] = v[i].w;
            }
        }
    }
    __syncthreads();
    // compute: rg = t>>5 (8 groups of 4 rows), e0 = (t&31)*4
    const int rg = t >> 5, e0 = (t & 31) * 4;
    float4 acc[4];
#pragma unroll
    for (int i = 0; i < 4; ++i) acc[i] = make_float4(0.f, 0.f, 0.f, 0.f);
    const float* cp = CovC + e0;
#pragma unroll 8
    for (int d = 0; d < DIM; ++d) {
        float4 cv = *(const float4*)(cp + (size_t)d * DIM);
        float4 av = *(const float4*)&aT[d][rg * 4];
        acc[0].x = fmaf(cv.x, av.x, acc[0].x);
        acc[0].y = fmaf(cv.y, av.x, acc[0].y);
        acc[0].z = fmaf(cv.z, av.x, acc[0].z);
        acc[0].w = fmaf(cv.w, av.x, acc[0].w);
        acc[1].x = fmaf(cv.x, av.y, acc[1].x);
        acc[1].y = fmaf(cv.y, av.y, acc[1].y);
        acc[1].z = fmaf(cv.z, av.y, acc[1].z);
        acc[1].w = fmaf(cv.w, av.y, acc[1].w);
        acc[2].x = fmaf(cv.x, av.z, acc[2].x);
        acc[2].y = fmaf(cv.y, av.z, acc[2].y);
        acc[2].z = fmaf(cv.z, av.z, acc[2].z);
        acc[2].w = fmaf(cv.w, av.z, acc[2].w);
        acc[3].x = fmaf(cv.x, av.w, acc[3].x);
        acc[3].y = fmaf(cv.y, av.w, acc[3].y);
        acc[3].z = fmaf(cv.z, av.w, acc[3].z);
        acc[3].w = fmaf(cv.w, av.w, acc[3].w);
    }
#pragma unroll
    for (int rr = 0; rr < 4; ++rr) {
        int rl2 = rg * 4 + rr;
        if (rl2 < nr) {
            int row = order[r0 + rl2];
            float ax = aT[e0 + 0][rl2], ay = aT[e0 + 1][rl2];
            float az = aT[e0 + 2][rl2], aw = aT[e0 + 3][rl2];
            ushort4 w;
            w.x = f2bf((ax + acc[rr].x * inv2t2) * invt);
            w.y = f2bf((ay + acc[rr].y * inv2t2) * invt);
            w.z = f2bf((az + acc[rr].z * inv2t2) * invt);
            w.w = f2bf((aw + acc[rr].w * inv2t2) * invt);
            *(ushort4*)(Wbf + (size_t)row * DIM + e0) = w;
        }
    }
}

// Block = 4 waves (2M x 2N). Block tile: 128 k-rows x 64 j-cols, K=128 unrolled.
// Wave tile: 64x32 via 4(m) x 2(n) mfma_f32_16x16x32_bf16.
// Per-lane online softmax (no cross-lane ops in j-loop); 16-lane merge at end.
// 3 blocks/CU (LDS 50.7 KB x 3 = 152 KB; VGPR cap 170).
__global__ __launch_bounds__(256, 3) void main_kernel(
    const unsigned short* __restrict__ Wbf, const unsigned short* __restrict__ Abf,
    float* __restrict__ mP, float* __restrict__ zP, float* __restrict__ sP,
    int Jsplit, int JSWEEP, int nP) {
    __shared__ __align__(16) unsigned short sW[128 * PITCH];
    __shared__ __align__(16) unsigned short sA[64 * PITCH];

    const int mb = blockIdx.x / Jsplit;
    const int jsp = blockIdx.x % Jsplit;
    const int rowBase = mb * 128;
    const int t = threadIdx.x;
    const int wave = t >> 6, lane = t & 63, quad = lane >> 4, l16 = lane & 15;
    const int waveM = wave >> 1, waveN = wave & 1;

    // stage W tile (128 rows x 128 bf16), once
    {
        int row = t >> 1, half = t & 1;
        const unsigned short* src = Wbf + (size_t)(rowBase + row) * DIM + half * 64;
        unsigned short* dst = sW + row * PITCH + half * 64;
#pragma unroll
        for (int i = 0; i < 8; i++)
            *(short8*)(dst + i * 8) = *(const short8*)(src + i * 8);
    }

    float run_m[4][4], run_Z[4][4], run_s[4][4];
#pragma unroll
    for (int a = 0; a < 4; a++)
#pragma unroll
        for (int r = 0; r < 4; r++) {
            run_m[a][r] = -3.4e38f; run_Z[a][r] = 0.f; run_s[a][r] = 0.f;
        }

    const unsigned short* myW = sW + (waveM * 64 + l16) * PITCH;
    const unsigned short* myA = sA + (waveN * 32 + l16) * PITCH;

    for (int js = 0; js < JSWEEP; ++js) {
        __syncthreads();  // protect sA overwrite (and sW on first iter)
        {   // stage A tile (64 rows x 128 bf16)
            int row = t >> 2, q = t & 3;
            int j0 = (jsp * JSWEEP + js) * 64;
            const unsigned short* src = Abf + (size_t)(j0 + row) * DIM + q * 32;
            unsigned short* dst = sA + row * PITCH + q * 32;
#pragma unroll
            for (int i = 0; i < 4; i++)
                *(short8*)(dst + i * 8) = *(const short8*)(src + i * 8);
        }
        __syncthreads();

        floatx4 acc[4][2];
#pragma unroll
        for (int mt = 0; mt < 4; mt++)
#pragma unroll
            for (int nt = 0; nt < 2; nt++) acc[mt][nt] = (floatx4)0.f;

#pragma unroll
        for (int kst = 0; kst < 4; ++kst) {
            const int koff = kst * 32 + quad * 8;
            short8 bfrag[2];
#pragma unroll
            for (int nt = 0; nt < 2; nt++)
                bfrag[nt] = *(const short8*)(myA + nt * 16 * PITCH + koff);
#pragma unroll
            for (int mt = 0; mt < 4; mt++) {
                short8 afrag = *(const short8*)(myW + mt * 16 * PITCH + koff);
#pragma unroll
                for (int nt = 0; nt < 2; nt++)
                    acc[mt][nt] = __builtin_amdgcn_mfma_f32_16x16x32_bf16(
                        afrag, bfrag[nt], acc[mt][nt], 0, 0, 0);
            }
        }

        // per-lane online softmax update (lane's 2 columns only; no shfl)
#pragma unroll
        for (int mt = 0; mt < 4; mt++)
#pragma unroll
            for (int r = 0; r < 4; r++) {
                float v0 = acc[mt][0][r], v1 = acc[mt][1][r];
                float tm = fmaxf(v0, v1);
                float nm = fmaxf(run_m[mt][r], tm);
                run_Z[mt][r] = run_Z[mt][r] * __expf(run_m[mt][r] - nm)
                             + __expf(v0 - nm) + __expf(v1 - nm);
                run_m[mt][r] = nm;
                run_s[mt][r] += v0 + v1;
            }
    }

    // merge across the 16 lanes sharing each row, then write partials
    const int chunk = jsp * 2 + waveN;
#pragma unroll
    for (int mt = 0; mt < 4; mt++)
#pragma unroll
        for (int r = 0; r < 4; r++) {
            float m = run_m[mt][r], Z = run_Z[mt][r], s = run_s[mt][r];
#pragma unroll
            for (int mask = 1; mask < 16; mask <<= 1) {
                float om = __shfl_xor(m, mask);
                float oZ = __shfl_xor(Z, mask);
                float os = __shfl_xor(s, mask);
                float nm = fmaxf(m, om);
                Z = Z * __expf(m - nm) + oZ * __expf(om - nm);
                m = nm;
                s += os;
            }
            if (l16 == r) {
                int row = rowBase + waveM * 64 + mt * 16 + quad * 4 + r;
                size_t idx = (size_t)row * nP + chunk;
                mP[idx] = m; zP[idx] = Z; sP[idx] = s;
            }
        }
}

// Grid = B blocks, 128 threads. Wave 0 merges the nP partials for row k and
// atomicAdds into per-class G. Last block (ticket) computes the final loss.
__global__ __launch_bounds__(128) void combine_kernel(
    const float* __restrict__ mP, const float* __restrict__ zP,
    const float* __restrict__ sP, const int* __restrict__ labels,
    double* __restrict__ G, const int* __restrict__ counts,
    int* __restrict__ ticket, float* __restrict__ out,
    int B, int nP, int C) {
    __shared__ int flag;
    __shared__ double sh[128];
    int k = blockIdx.x;
    int t = threadIdx.x;
    if (t < 64) {
        float m = -3.4e38f, Z = 0.0f, s = 0.0f;
        if (t < nP) {
            size_t idx = (size_t)k * nP + t;
            m = mP[idx]; Z = zP[idx]; s = sP[idx];
        }
        float M = m;
#pragma unroll
        for (int o = 32; o > 0; o >>= 1) M = fmaxf(M, __shfl_xor(M, o));
        float zt = Z * __expf(m - M);
        float st = s;
#pragma unroll
        for (int o = 32; o > 0; o >>= 1) {
            zt += __shfl_xor(zt, o);
            st += __shfl_xor(st, o);
        }
        if (t == 0) {
            double Sk = (double)st - (double)B * (double)M
                        - (double)B * log((double)zt + 1e-12);
            atomicAdd(&G[labels[k]], Sk);
        }
    }
    __threadfence();
    __syncthreads();
    if (t == 0) flag = (atomicAdd(ticket, 1) == (int)gridDim.x - 1);
    __syncthreads();
    if (flag) {
        __threadfence();
        double v = 0.0;
        if (t < C) {
            double g = atomicAdd(&G[t], 0.0);   // device-scope coherent read
            double cnt = (double)counts[t];
            v = g * (cnt / (cnt + 1e-12));
        }
        sh[t] = v;
        __syncthreads();
        for (int o = 64; o > 0; o >>= 1) {
            if (t < o) sh[t] += sh[t + o];
            __syncthreads();
        }
        if (t == 0)
            out[0] = (float)(-sh[0] / ((double)B * (double)B));
    }
}

extern "C" void kernel_launch(void* const* d_in, const int* in_sizes, int n_in,
                              void* d_out, int out_size, void* d_ws, size_t ws_size,
                              hipStream_t stream) {
    const float* A = (const float*)d_in[0];
    const int* labels = (const int*)d_in[1];
    const float* Cov = (const float*)d_in[2];
    float* out = (float*)d_out;

    int B = in_sizes[0] / DIM;            // 4096
    int C = in_sizes[2] / (DIM * DIM);    // 100
    int Jsplit = 16;
    int JSWEEP = B / (Jsplit * 64);       // 4
    int nP = Jsplit * 2;                  // 32 partials per row

    char* ws = (char*)d_ws;
    unsigned short* Wbf = (unsigned short*)ws;                       // B*128 bf16
    unsigned short* Abf = Wbf + (size_t)B * DIM;                     // B*128 bf16
    float* mP = (float*)(Abf + (size_t)B * DIM);                     // B*nP f32
    float* zP = mP + (size_t)B * nP;
    float* sP = zP + (size_t)B * nP;
    double* G = (double*)(sP + (size_t)B * nP);                      // C doubles
    int* counts = (int*)(G + C);                                     // C ints
    int* order = counts + C;                                         // B ints
    int* classStart = order + B;                                     // C+1 ints
    int* ticket = classStart + C + 1;                                // 1 int

    sort_kernel<<<1, 1024, 0, stream>>>(labels, order, classStart, counts,
                                        G, ticket, B, C);
    wbuild_kernel<<<C * TILES, 256, 0, stream>>>(A, Cov, order, classStart,
                                                 Wbf, Abf);
    main_kernel<<<(B / 128) * Jsplit, 256, 0, stream>>>(Wbf, Abf, mP, zP, sP,
                                                        Jsplit, JSWEEP, nP);
    combine_kernel<<<B, 128, 0, stream>>>(mP, zP, sP, labels, G, counts,
                                          ticket, out, B, nP, C);
}

// Round 8
// 100.470 us; speedup vs baseline: 2.6142x; 2.6142x over previous
//
#include <hip/hip_runtime.h>
#include <hip/hip_bf16.h>

// ContrastiveLoss: B=4096 rows, D=128 feature dim, C=100 classes.
// loss = -(1/B^2) * sum_k S_k * w_{l_k},  w_c = count_c/(count_c+1e-12)
//   S_k  = sum_j logits[k,j] - B*m_k - B*log(Z_k + 1e-12)
//   logits[k,j] = w_k . a_j,  w_k = (a_k + (a_k @ Cov[l_k]) / (2 T^2)) / T
// 4 dispatches: prep (bf16 conv + W build), main (MFMA flash logits,
// XOR-swizzled LDS + A-tile register prefetch), combine (S_k per row,
// no atomics), final (1-block label histogram + weighted sum).
// LESSONS: (R4) heavy fp64 tails fused into the MFMA kernel wreck regalloc
// (VGPR 68, spills). (R7) single-address global tickets at 4096-block scale
// serialize to ~145us. Neither pattern may return.

#define DIM 128
#define TEMP 0.07f

typedef __attribute__((ext_vector_type(8))) short short8;
typedef __attribute__((ext_vector_type(4))) float floatx4;

static __device__ __forceinline__ unsigned short f2bf(float f) {
    __hip_bfloat16 h = __float2bfloat16(f);
    union { __hip_bfloat16 h; unsigned short u; } c;
    c.h = h;
    return c.u;
}

// 2 rows per block (256 threads). Writes Abf (bf16 copy of A) and
// Wbf = bf16((a + (a @ Cov[l]) / (2T^2)) / T).
__global__ __launch_bounds__(256) void prep_kernel(
    const float* __restrict__ A, const int* __restrict__ labels,
    const float* __restrict__ Cov, unsigned short* __restrict__ Wbf,
    unsigned short* __restrict__ Abf) {
    const float inv2t2 = 1.0f / (2.0f * TEMP * TEMP);
    const float invt = 1.0f / TEMP;
    const int sub = threadIdx.x >> 7;   // which of 2 rows
    const int e = threadIdx.x & 127;
    const int i = blockIdx.x * 2 + sub;
    __shared__ float a[2][DIM];
    float av = A[(size_t)i * DIM + e];
    a[sub][e] = av;
    Abf[(size_t)i * DIM + e] = f2bf(av);
    __syncthreads();
    int c = labels[i];
    const float* Cp = Cov + (size_t)c * (DIM * DIM) + e;
    float acc = 0.0f;
#pragma unroll 8
    for (int d = 0; d < DIM; ++d) {
        acc = fmaf(a[sub][d], Cp[(size_t)d * DIM], acc);
    }
    Wbf[(size_t)i * DIM + e] = f2bf((av + acc * inv2t2) * invt);
}

// Block = 4 waves (2M x 2N). Block tile: 128 k-rows x 64 j-cols, K=128
// unrolled. Wave tile: 64x32 via 4(m) x 2(n) mfma_f32_16x16x32_bf16.
// LDS: PITCH=128, 16B-chunk XOR swizzle (chunk c of row r at c^(r&15)) ->
// fragment ds_read_b128 conflict-free (16 lanes hit 16 distinct chunks).
// A-tile staged via register prefetch issued after the compute barrier so
// the vmcnt drain overlaps MFMA+softmax of the current tile.
// Per-lane online softmax; 16-lane merge at end. grid = 32 mb x 16 jsp.
__global__ __launch_bounds__(256, 2) void main_kernel(
    const unsigned short* __restrict__ Wbf, const unsigned short* __restrict__ Abf,
    float* __restrict__ mP, float* __restrict__ zP, float* __restrict__ sP,
    int Jsplit, int JSWEEP, int nP) {
    __shared__ __align__(16) unsigned short sW[128 * 128];  // 32 KB
    __shared__ __align__(16) unsigned short sA[64 * 128];   // 16 KB

    const int mb = blockIdx.x / Jsplit;
    const int jsp = blockIdx.x % Jsplit;
    const int rowBase = mb * 128;
    const int t = threadIdx.x;
    const int wave = t >> 6, lane = t & 63, quad = lane >> 4, l16 = lane & 15;
    const int waveM = wave >> 1, waveN = wave & 1;

    // stage W tile (128 rows x 128 bf16), swizzled, once
    {
        int row = t >> 1, half = t & 1, rsw = row & 15;
        const unsigned short* src = Wbf + (size_t)(rowBase + row) * DIM + half * 64;
        unsigned short* dstrow = sW + row * 128;
#pragma unroll
        for (int i = 0; i < 8; i++) {
            int c = half * 8 + i;
            *(short8*)(dstrow + ((c ^ rsw) << 3)) = *(const short8*)(src + i * 8);
        }
    }

    float run_m[4][4], run_Z[4][4], run_s[4][4];
#pragma unroll
    for (int a = 0; a < 4; a++)
#pragma unroll
        for (int r = 0; r < 4; r++) {
            run_m[a][r] = -3.4e38f; run_Z[a][r] = 0.f; run_s[a][r] = 0.f;
        }

    // A-tile staging descriptors (thread -> row, quarter)
    const int arow = t >> 2, aq = t & 3, arsw = arow & 15;
    const unsigned short* asrc0 =
        Abf + (size_t)(jsp * JSWEEP * 64 + arow) * DIM + aq * 32;
    unsigned short* adst = sA + arow * 128;

    short8 pre[4];
#pragma unroll
    for (int i = 0; i < 4; i++) pre[i] = *(const short8*)(asrc0 + i * 8);

    const unsigned short* myW = sW + (size_t)(waveM * 64 + l16) * 128;
    const unsigned short* myA = sA + (size_t)(waveN * 32 + l16) * 128;

    for (int js = 0; js < JSWEEP; ++js) {
        __syncthreads();  // sA free to overwrite (prefetched loads long done)
#pragma unroll
        for (int i = 0; i < 4; i++) {
            int c = aq * 4 + i;
            *(short8*)(adst + ((c ^ arsw) << 3)) = pre[i];
        }
        __syncthreads();  // sA (and sW on first iter) ready

        if (js + 1 < JSWEEP) {  // issue next tile's loads; drain hides in compute
            const unsigned short* nsrc = asrc0 + (size_t)(js + 1) * 64 * DIM;
#pragma unroll
            for (int i = 0; i < 4; i++) pre[i] = *(const short8*)(nsrc + i * 8);
        }

        floatx4 acc[4][2];
#pragma unroll
        for (int mt = 0; mt < 4; mt++)
#pragma unroll
            for (int nt = 0; nt < 2; nt++) acc[mt][nt] = (floatx4)0.f;

#pragma unroll
        for (int kst = 0; kst < 4; ++kst) {
            const int coff = (((kst << 2) | quad) ^ l16) << 3;
            short8 bfrag[2];
#pragma unroll
            for (int nt = 0; nt < 2; nt++)
                bfrag[nt] = *(const short8*)(myA + nt * 16 * 128 + coff);
#pragma unroll
            for (int mt = 0; mt < 4; mt++) {
                short8 afrag = *(const short8*)(myW + mt * 16 * 128 + coff);
#pragma unroll
                for (int nt = 0; nt < 2; nt++)
                    acc[mt][nt] = __builtin_amdgcn_mfma_f32_16x16x32_bf16(
                        afrag, bfrag[nt], acc[mt][nt], 0, 0, 0);
            }
        }

        // per-lane online softmax update (lane's 2 columns only; no shfl)
#pragma unroll
        for (int mt = 0; mt < 4; mt++)
#pragma unroll
            for (int r = 0; r < 4; r++) {
                float v0 = acc[mt][0][r], v1 = acc[mt][1][r];
                float tm = fmaxf(v0, v1);
                float nm = fmaxf(run_m[mt][r], tm);
                run_Z[mt][r] = run_Z[mt][r] * __expf(run_m[mt][r] - nm)
                             + __expf(v0 - nm) + __expf(v1 - nm);
                run_m[mt][r] = nm;
                run_s[mt][r] += v0 + v1;
            }
    }

    // merge across the 16 lanes sharing each row, then write partials
    const int chunk = jsp * 2 + waveN;
#pragma unroll
    for (int mt = 0; mt < 4; mt++)
#pragma unroll
        for (int r = 0; r < 4; r++) {
            float m = run_m[mt][r], Z = run_Z[mt][r], s = run_s[mt][r];
#pragma unroll
            for (int mask = 1; mask < 16; mask <<= 1) {
                float om = __shfl_xor(m, mask);
                float oZ = __shfl_xor(Z, mask);
                float os = __shfl_xor(s, mask);
                float nm = fmaxf(m, om);
                Z = Z * __expf(m - nm) + oZ * __expf(om - nm);
                m = nm;
                s += os;
            }
            if (l16 == r) {
                int row = rowBase + waveM * 64 + mt * 16 + quad * 4 + r;
                size_t idx = (size_t)row * nP + chunk;
                mP[idx] = m; zP[idx] = Z; sP[idx] = s;
            }
        }
}

// One wave per row k: merge nP partial (m,Z,s) triples, write S_k (double).
__global__ __launch_bounds__(64) void combine_kernel(
    const float* __restrict__ mP, const float* __restrict__ zP,
    const float* __restrict__ sP, double* __restrict__ Sk, int B, int nP) {
    int k = blockIdx.x;
    int l = threadIdx.x;
    float m = -3.4e38f, Z = 0.0f, s = 0.0f;
    if (l < nP) {
        size_t idx = (size_t)k * nP + l;
        m = mP[idx]; Z = zP[idx]; s = sP[idx];
    }
    float M = m;
#pragma unroll
    for (int o = 32; o > 0; o >>= 1) M = fmaxf(M, __shfl_xor(M, o));
    float zt = Z * __expf(m - M);
    float st = s;
#pragma unroll
    for (int o = 32; o > 0; o >>= 1) {
        zt += __shfl_xor(zt, o);
        st += __shfl_xor(st, o);
    }
    if (l == 0) {
        Sk[k] = (double)st - (double)B * (double)M
                - (double)B * log((double)zt + 1e-12);
    }
}

// One block: histogram labels in LDS, then loss = -(1/B^2) sum_k S_k * w_{l_k}.
__global__ __launch_bounds__(1024) void final_kernel(
    const double* __restrict__ Sk, const int* __restrict__ labels,
    float* __restrict__ out, int B) {
    __shared__ int hist[128];
    __shared__ double sh[1024];
    int t = threadIdx.x;
    if (t < 128) hist[t] = 0;
    __syncthreads();
    for (int i = t; i < B; i += 1024) atomicAdd(&hist[labels[i]], 1);
    __syncthreads();
    double acc = 0.0;
    for (int i = t; i < B; i += 1024) {
        double cnt = (double)hist[labels[i]];
        acc += Sk[i] * (cnt / (cnt + 1e-12));
    }
    sh[t] = acc;
    __syncthreads();
    for (int o = 512; o > 0; o >>= 1) {
        if (t < o) sh[t] += sh[t + o];
        __syncthreads();
    }
    if (t == 0) out[0] = (float)(-sh[0] / ((double)B * (double)B));
}

extern "C" void kernel_launch(void* const* d_in, const int* in_sizes, int n_in,
                              void* d_out, int out_size, void* d_ws, size_t ws_size,
                              hipStream_t stream) {
    const float* A = (const float*)d_in[0];
    const int* labels = (const int*)d_in[1];
    const float* Cov = (const float*)d_in[2];
    float* out = (float*)d_out;

    int B = in_sizes[0] / DIM;            // 4096
    int Jsplit = 16;
    int JSWEEP = B / (Jsplit * 64);       // 4
    int nP = Jsplit * 2;                  // 32 partials per row

    char* ws = (char*)d_ws;
    unsigned short* Wbf = (unsigned short*)ws;                       // B*128 bf16
    unsigned short* Abf = Wbf + (size_t)B * DIM;                     // B*128 bf16
    float* mP = (float*)(Abf + (size_t)B * DIM);                     // B*nP f32
    float* zP = mP + (size_t)B * nP;
    float* sP = zP + (size_t)B * nP;
    double* Sk = (double*)(sP + (size_t)B * nP);                     // B doubles

    prep_kernel<<<B / 2, 256, 0, stream>>>(A, labels, Cov, Wbf, Abf);
    main_kernel<<<(B / 128) * Jsplit, 256, 0, stream>>>(Wbf, Abf, mP, zP, sP,
                                                        Jsplit, JSWEEP, nP);
    combine_kernel<<<B, 64, 0, stream>>>(mP, zP, sP, Sk, B, nP);
    final_kernel<<<1, 1024, 0, stream>>>(Sk, labels, out, B);
}